// Round 3
// baseline (592.579 us; speedup 1.0000x reference)
//
#include <hip/hip_runtime.h>
#include <hip/hip_bf16.h>
#include <stdint.h>

// GraphNet global block, MI355X.
// R3: node MLP is ROW-INDEPENDENT -> retile so each wave owns 32 rows end-to-
// end. Zero __syncthreads in node_kernel (all LDS wave-private, in-order DS
// pipe). Sort dropped (R2: ~200us side cost + scattered x-gather, no win).
// Atomic scatter kept (R2 proved atomics were not the R0 bottleneck).
// Phase 2 = f16 MFMA graph2 (verified in R2). agg aliases d_out (read in
// graph2 staging before overwrite; rows block-exclusive).

#define NNODES 500000
#define NGRAPHS 4096
#define LDH 136       // padded f16 row stride (272 B: 16B-aligned, conflict-free)

typedef __attribute__((ext_vector_type(8))) _Float16 half8;
typedef __attribute__((ext_vector_type(4))) float floatx4;

// ---------------- prep: transpose all six weights to f16 [N][K] -------------
__global__ void prep_kernel(const float* __restrict__ w1, const float* __restrict__ w2,
                            const float* __restrict__ w3, const float* __restrict__ w4,
                            const float* __restrict__ w5, const float* __restrict__ w6,
                            _Float16* __restrict__ w1T, _Float16* __restrict__ w2T,
                            _Float16* __restrict__ w3T, _Float16* __restrict__ w4T,
                            _Float16* __restrict__ w5T, _Float16* __restrict__ w6T) {
    int i = blockIdx.x * 256 + threadIdx.x;   // 0..16383
    if (i < 128 * 128) {
        int n = i >> 7, k = i & 127;
        w1T[i] = (_Float16)w1[k * 128 + n];
        w2T[i] = (_Float16)w2[k * 128 + n];
        w4T[i] = (_Float16)w4[k * 128 + n];
        w5T[i] = (_Float16)w5[k * 128 + n];
    }
    if (i < 64 * 128) {
        int n = i >> 7, k = i & 127;
        w3T[i] = (_Float16)w3[k * 64 + n];
        w6T[i] = (_Float16)w6[k * 64 + n];
    }
}

// ---------------- phase 1: barrier-free per-wave node MLP + LN + scatter ----
// Each wave processes 32 rows through all 3 layers. 500000 = 32*15625 exactly,
// so a wave either has a full 32-row tile or nothing.
__global__ __launch_bounds__(256, 4) void node_kernel(
    const float* __restrict__ x, const float* __restrict__ u,
    const int* __restrict__ batch,
    const _Float16* __restrict__ w1T, const _Float16* __restrict__ w2T,
    const _Float16* __restrict__ w3T,
    const float* __restrict__ b1, const float* __restrict__ b2, const float* __restrict__ b3,
    const float* __restrict__ lng, const float* __restrict__ lnb,
    float* __restrict__ agg)
{
    __shared__ __align__(16) _Float16 hA[4][32 * LDH];   // per-wave private 8.7KB

    const int tid = threadIdx.x;
    const int wave = tid >> 6;
    const int lane = tid & 63;
    const int q = lane >> 4;
    const int l16 = lane & 15;
    const int wid = blockIdx.x * 4 + wave;
    const int rowbase = wid * 32;
    if (rowbase >= NNODES) return;              // no barriers below -> safe
    _Float16* hw = hA[wave];

    // hoist LN params (reused at the end)
    float gct[4], bct[4];
    #pragma unroll
    for (int ct = 0; ct < 4; ++ct) {
        gct[ct] = lng[ct * 16 + l16];
        bct[ct] = lnb[ct * 16 + l16];
    }

    // ---- stage: 32 rows x 128 f16 cols = concat(x, u[batch]) ----
    // 1024 float4 chunks; lane handles chunks lane+64k (16 per lane), coalesced.
    #pragma unroll
    for (int k = 0; k < 16; ++k) {
        int c = lane + k * 64;          // 0..1023
        int r = c >> 5;                 // 0..31
        int cc = c & 31;                // float4 index within 128-col row
        int gr = rowbase + r;
        float4 v;
        if (cc < 16) {
            v = *(const float4*)(x + (size_t)gr * 64 + cc * 4);
        } else {
            int g = batch[gr];
            v = *(const float4*)(u + (size_t)g * 64 + (cc - 16) * 4);
        }
        _Float16* p = &hw[r * LDH + cc * 4];
        p[0] = (_Float16)v.x; p[1] = (_Float16)v.y;
        p[2] = (_Float16)v.z; p[3] = (_Float16)v.w;
    }
    // compiler inserts lgkmcnt before first dependent ds_read; DS pipe is
    // in-order per wave -> no barrier needed (LDS region is wave-private).

    // ---- layers 1 & 2: 32x128 @ 128x128, relu, in-place ----
    for (int layer = 0; layer < 2; ++layer) {
        const _Float16* wT = layer ? w2T : w1T;
        const float* bias = layer ? b2 : b1;
        #pragma unroll
        for (int rt = 0; rt < 2; ++rt) {
            // preload this 16-row group's A fragments (frees rows for overwrite)
            half8 af[4];
            #pragma unroll
            for (int ks = 0; ks < 4; ++ks)
                af[ks] = *(const half8*)(&hw[(rt * 16 + l16) * LDH + ks * 32 + q * 8]);
            floatx4 acc[8];
            #pragma unroll
            for (int ct = 0; ct < 8; ++ct) {
                float bv = bias[ct * 16 + l16];
                acc[ct] = (floatx4){bv, bv, bv, bv};
            }
            #pragma unroll
            for (int ct = 0; ct < 8; ++ct)
                #pragma unroll
                for (int ks = 0; ks < 4; ++ks) {
                    half8 bf = *(const half8*)(wT + (ct * 16 + l16) * 128 + ks * 32 + q * 8);
                    acc[ct] = __builtin_amdgcn_mfma_f32_16x16x32_f16(af[ks], bf, acc[ct], 0, 0, 0);
                }
            // writeback: rows rt*16 + q*4 + j (disjoint from rt=1's reads)
            #pragma unroll
            for (int ct = 0; ct < 8; ++ct)
                #pragma unroll
                for (int j = 0; j < 4; ++j) {
                    float v = acc[ct][j];
                    v = v > 0.f ? v : 0.f;
                    hw[(rt * 16 + q * 4 + j) * LDH + ct * 16 + l16] = (_Float16)v;
                }
        }
    }

    // ---- layer 3: 32x64 + LN + atomic scatter ----
    #pragma unroll
    for (int rt = 0; rt < 2; ++rt) {
        half8 af[4];
        #pragma unroll
        for (int ks = 0; ks < 4; ++ks)
            af[ks] = *(const half8*)(&hw[(rt * 16 + l16) * LDH + ks * 32 + q * 8]);
        floatx4 acc[4];
        #pragma unroll
        for (int ct = 0; ct < 4; ++ct) {
            float bv = b3[ct * 16 + l16];
            acc[ct] = (floatx4){bv, bv, bv, bv};
        }
        #pragma unroll
        for (int ct = 0; ct < 4; ++ct)
            #pragma unroll
            for (int ks = 0; ks < 4; ++ks) {
                half8 bf = *(const half8*)(w3T + (ct * 16 + l16) * 128 + ks * 32 + q * 8);
                acc[ct] = __builtin_amdgcn_mfma_f32_16x16x32_f16(af[ks], bf, acc[ct], 0, 0, 0);
            }
        #pragma unroll
        for (int j = 0; j < 4; ++j) {
            int rloc = rt * 16 + q * 4 + j;       // quad-uniform row
            float v0 = acc[0][j], v1 = acc[1][j];
            float v2 = acc[2][j], v3 = acc[3][j];
            float s = v0 + v1 + v2 + v3;
            float ss = v0 * v0 + v1 * v1 + v2 * v2 + v3 * v3;
            #pragma unroll
            for (int m = 1; m < 16; m <<= 1) {
                s += __shfl_xor(s, m, 16);
                ss += __shfl_xor(ss, m, 16);
            }
            float mean = s * (1.f / 64.f);
            float var = ss * (1.f / 64.f) - mean * mean;
            float rstd = rsqrtf(var + 1e-5f);
            int g = batch[rowbase + rloc];         // L1-hot (read at staging)
            float* dst = agg + (size_t)g * 64;
            unsafeAtomicAdd(dst + 0 + l16,  (v0 - mean) * rstd * gct[0] + bct[0]);
            unsafeAtomicAdd(dst + 16 + l16, (v1 - mean) * rstd * gct[1] + bct[1]);
            unsafeAtomicAdd(dst + 32 + l16, (v2 - mean) * rstd * gct[2] + bct[2]);
            unsafeAtomicAdd(dst + 48 + l16, (v3 - mean) * rstd * gct[3] + bct[3]);
        }
    }
}

// ---------------- phase 2: per-graph MLP, f16 MFMA (32 blocks x 128 rows) ---
__global__ __launch_bounds__(256, 2) void graph2_kernel(
    const float* __restrict__ u,
    const _Float16* __restrict__ w4T, const _Float16* __restrict__ w5T,
    const _Float16* __restrict__ w6T,
    const float* __restrict__ b4, const float* __restrict__ b5, const float* __restrict__ b6,
    const float* __restrict__ lng, const float* __restrict__ lnb,
    float* __restrict__ out)   // out holds agg on entry; rows block-exclusive
{
    __shared__ __align__(16) _Float16 hA[128 * LDH];

    const int tid = threadIdx.x;
    const int rowbase = blockIdx.x * 128;
    const int wave = tid >> 6;
    const int lane = tid & 63;
    const int q = lane >> 4;
    const int l16 = lane & 15;

    // stage g0 = concat(agg, u) as f16
    for (int i = tid; i < 128 * 16; i += 256) {
        int r = i >> 4, c4 = (i & 15) << 2;
        int g = rowbase + r;
        float4 va = *(const float4*)(out + (size_t)g * 64 + c4);
        _Float16* p = &hA[r * LDH + c4];
        p[0] = (_Float16)va.x; p[1] = (_Float16)va.y;
        p[2] = (_Float16)va.z; p[3] = (_Float16)va.w;
        float4 vu = *(const float4*)(u + (size_t)g * 64 + c4);
        _Float16* p2 = &hA[r * LDH + 64 + c4];
        p2[0] = (_Float16)vu.x; p2[1] = (_Float16)vu.y;
        p2[2] = (_Float16)vu.z; p2[3] = (_Float16)vu.w;
    }
    __syncthreads();

    // ---- layers 4 & 5: 128x128, relu, in-place ----
    const int rowg = (wave >> 1) * 64;
    const int colg = (wave & 1) * 64;
    for (int layer = 0; layer < 2; ++layer) {
        const _Float16* wT = layer ? w5T : w4T;
        const float* bias = layer ? b5 : b4;
        floatx4 acc[4][4];
        #pragma unroll
        for (int ct = 0; ct < 4; ++ct) {
            float bv = bias[colg + ct * 16 + l16];
            #pragma unroll
            for (int rt = 0; rt < 4; ++rt) acc[rt][ct] = (floatx4){bv, bv, bv, bv};
        }
        half8 bfr[4][4];
        #pragma unroll
        for (int ks = 0; ks < 4; ++ks)
            #pragma unroll
            for (int ct = 0; ct < 4; ++ct)
                bfr[ks][ct] = *(const half8*)(wT + (colg + ct * 16 + l16) * 128 + ks * 32 + q * 8);
        #pragma unroll
        for (int ks = 0; ks < 4; ++ks) {
            half8 af[4];
            #pragma unroll
            for (int rt = 0; rt < 4; ++rt)
                af[rt] = *(const half8*)(&hA[(rowg + rt * 16 + l16) * LDH + ks * 32 + q * 8]);
            #pragma unroll
            for (int rt = 0; rt < 4; ++rt)
                #pragma unroll
                for (int ct = 0; ct < 4; ++ct)
                    acc[rt][ct] = __builtin_amdgcn_mfma_f32_16x16x32_f16(
                        af[rt], bfr[ks][ct], acc[rt][ct], 0, 0, 0);
        }
        __syncthreads();
        #pragma unroll
        for (int rt = 0; rt < 4; ++rt)
            #pragma unroll
            for (int ct = 0; ct < 4; ++ct)
                #pragma unroll
                for (int j = 0; j < 4; ++j) {
                    float v = acc[rt][ct][j];
                    v = v > 0.f ? v : 0.f;
                    hA[(rowg + rt * 16 + q * 4 + j) * LDH + colg + ct * 16 + l16] = (_Float16)v;
                }
        __syncthreads();
    }

    // ---- layer 6: 128x64 + LN + residual + store ----
    {
        const int rowg3 = wave * 32;
        floatx4 acc[2][4];
        #pragma unroll
        for (int ct = 0; ct < 4; ++ct) {
            float bv = b6[ct * 16 + l16];
            acc[0][ct] = (floatx4){bv, bv, bv, bv};
            acc[1][ct] = (floatx4){bv, bv, bv, bv};
        }
        half8 bfr[4][4];
        #pragma unroll
        for (int ks = 0; ks < 4; ++ks)
            #pragma unroll
            for (int ct = 0; ct < 4; ++ct)
                bfr[ks][ct] = *(const half8*)(w6T + (ct * 16 + l16) * 128 + ks * 32 + q * 8);
        #pragma unroll
        for (int ks = 0; ks < 4; ++ks) {
            half8 af[2];
            #pragma unroll
            for (int rt = 0; rt < 2; ++rt)
                af[rt] = *(const half8*)(&hA[(rowg3 + rt * 16 + l16) * LDH + ks * 32 + q * 8]);
            #pragma unroll
            for (int rt = 0; rt < 2; ++rt)
                #pragma unroll
                for (int ct = 0; ct < 4; ++ct)
                    acc[rt][ct] = __builtin_amdgcn_mfma_f32_16x16x32_f16(
                        af[rt], bfr[ks][ct], acc[rt][ct], 0, 0, 0);
        }
        float gct[4], bct[4];
        #pragma unroll
        for (int ct = 0; ct < 4; ++ct) {
            gct[ct] = lng[ct * 16 + l16];
            bct[ct] = lnb[ct * 16 + l16];
        }
        #pragma unroll
        for (int rt = 0; rt < 2; ++rt)
            #pragma unroll
            for (int j = 0; j < 4; ++j) {
                int rloc = rowg3 + rt * 16 + q * 4 + j;
                size_t g = (size_t)(rowbase + rloc);
                float v0 = acc[rt][0][j], v1 = acc[rt][1][j];
                float v2 = acc[rt][2][j], v3 = acc[rt][3][j];
                float s = v0 + v1 + v2 + v3;
                float ss = v0 * v0 + v1 * v1 + v2 * v2 + v3 * v3;
                #pragma unroll
                for (int m = 1; m < 16; m <<= 1) {
                    s += __shfl_xor(s, m, 16);
                    ss += __shfl_xor(ss, m, 16);
                }
                float mean = s * (1.f / 64.f);
                float var = ss * (1.f / 64.f) - mean * mean;
                float rstd = rsqrtf(var + 1e-5f);
                out[g * 64 + 0 + l16]  = (v0 - mean) * rstd * gct[0] + bct[0] + u[g * 64 + 0 + l16];
                out[g * 64 + 16 + l16] = (v1 - mean) * rstd * gct[1] + bct[1] + u[g * 64 + 16 + l16];
                out[g * 64 + 32 + l16] = (v2 - mean) * rstd * gct[2] + bct[2] + u[g * 64 + 32 + l16];
                out[g * 64 + 48 + l16] = (v3 - mean) * rstd * gct[3] + bct[3] + u[g * 64 + 48 + l16];
            }
    }
}

extern "C" void kernel_launch(void* const* d_in, const int* in_sizes, int n_in,
                              void* d_out, int out_size, void* d_ws, size_t ws_size,
                              hipStream_t stream) {
    const float* x   = (const float*)d_in[0];
    const float* u   = (const float*)d_in[1];
    const int*   bt  = (const int*)d_in[2];
    const float* w1  = (const float*)d_in[3];
    const float* b1  = (const float*)d_in[4];
    const float* w2  = (const float*)d_in[5];
    const float* b2  = (const float*)d_in[6];
    const float* w3  = (const float*)d_in[7];
    const float* b3  = (const float*)d_in[8];
    const float* lng = (const float*)d_in[9];
    const float* lnb = (const float*)d_in[10];
    const float* w4  = (const float*)d_in[11];
    const float* b4  = (const float*)d_in[12];
    const float* w5  = (const float*)d_in[13];
    const float* b5  = (const float*)d_in[14];
    const float* w6  = (const float*)d_in[15];
    const float* b6  = (const float*)d_in[16];
    const float* g2  = (const float*)d_in[17];
    const float* bb2 = (const float*)d_in[18];
    float* out = (float*)d_out;

    // workspace: 6 f16 weight transposes (160 KB)
    _Float16* w1T = (_Float16*)d_ws;
    _Float16* w2T = w1T + 128 * 128;
    _Float16* w3T = w2T + 128 * 128;
    _Float16* w4T = w3T + 64 * 128;
    _Float16* w5T = w4T + 128 * 128;
    _Float16* w6T = w5T + 128 * 128;

    hipMemsetAsync(d_out, 0, (size_t)NGRAPHS * 64 * sizeof(float), stream);
    prep_kernel<<<64, 256, 0, stream>>>(w1, w2, w3, w4, w5, w6,
                                        w1T, w2T, w3T, w4T, w5T, w6T);
    // 500000/32 = 15625 waves; 4 waves/block
    node_kernel<<<(15625 + 3) / 4, 256, 0, stream>>>(
        x, u, bt, w1T, w2T, w3T, b1, b2, b3, lng, lnb, out);
    graph2_kernel<<<NGRAPHS / 128, 256, 0, stream>>>(
        u, w4T, w5T, w6T, b4, b5, b6, g2, bb2, out);
}

// Round 6
// 425.521 us; speedup vs baseline: 1.3926x; 1.3926x over previous
//
#include <hip/hip_runtime.h>
#include <hip/hip_bf16.h>
#include <stdint.h>

// GraphNet global block, MI355X.
// R4/R6: clean atomic-removal test. Node kernel = R0 structure (222us, batched
// weight prefetch into regs, coalesced x reads) except the tail: LN output ->
// LDS -> coalesced f16 store to global h3[] (64MB) instead of 32M fp32 atomics
// (R0/R3 signature: WRITE_SIZE=125MB = atomic payload written through to HBM).
// Aggregation = separate pass in SORTED node order (hist/scan/scatter,
// R2-verified), one wave per 128 sorted rows, lane=column, register
// run-accumulate, flush at graph boundary -> ~0.78M atomics.
// R6 FIX: R5's copy-out stored only 16 f16/lane (cols 16-31,48-63 of each h3
// row left uninitialized -> absmax 2.43). Now 4x half8 = 32 f16/lane.

#define NNODES 500000
#define NGRAPHS 4096
#define ROWS 128      // node rows per block
#define LDH 136       // padded f16 row stride (272 B: 16B-aligned, conflict-free)

typedef __attribute__((ext_vector_type(8))) _Float16 half8;
typedef __attribute__((ext_vector_type(4))) float floatx4;

// ---------------- prep: transpose all six weights to f16 [N][K] -------------
__global__ void prep_kernel(const float* __restrict__ w1, const float* __restrict__ w2,
                            const float* __restrict__ w3, const float* __restrict__ w4,
                            const float* __restrict__ w5, const float* __restrict__ w6,
                            _Float16* __restrict__ w1T, _Float16* __restrict__ w2T,
                            _Float16* __restrict__ w3T, _Float16* __restrict__ w4T,
                            _Float16* __restrict__ w5T, _Float16* __restrict__ w6T) {
    int i = blockIdx.x * 256 + threadIdx.x;   // 0..16383
    if (i < 128 * 128) {
        int n = i >> 7, k = i & 127;
        w1T[i] = (_Float16)w1[k * 128 + n];
        w2T[i] = (_Float16)w2[k * 128 + n];
        w4T[i] = (_Float16)w4[k * 128 + n];
        w5T[i] = (_Float16)w5[k * 128 + n];
    }
    if (i < 64 * 128) {
        int n = i >> 7, k = i & 127;
        w3T[i] = (_Float16)w3[k * 64 + n];
        w6T[i] = (_Float16)w6[k * 64 + n];
    }
}

// ---------------- counting sort: hist -> scan -> scatter --------------------
__global__ void hist_kernel(const int* __restrict__ batch, int* __restrict__ cnt) {
    __shared__ int h[NGRAPHS];
    for (int i = threadIdx.x; i < NGRAPHS; i += 256) h[i] = 0;
    __syncthreads();
    for (int i = blockIdx.x * 256 + threadIdx.x; i < NNODES; i += 64 * 256)
        atomicAdd(&h[batch[i]], 1);
    __syncthreads();
    for (int i = threadIdx.x; i < NGRAPHS; i += 256) {
        int v = h[i];
        if (v) atomicAdd(&cnt[i], v);
    }
}

__global__ void scan_kernel(const int* __restrict__ cnt, int* __restrict__ runoff) {
    __shared__ int partial[256];
    int tid = threadIdx.x;
    int local[16];
    int s = 0;
    #pragma unroll
    for (int j = 0; j < 16; ++j) { local[j] = cnt[tid * 16 + j]; s += local[j]; }
    partial[tid] = s;
    __syncthreads();
    for (int off = 1; off < 256; off <<= 1) {
        int v = (tid >= off) ? partial[tid - off] : 0;
        __syncthreads();
        partial[tid] += v;
        __syncthreads();
    }
    int run = partial[tid] - s;
    #pragma unroll
    for (int j = 0; j < 16; ++j) { runoff[tid * 16 + j] = run; run += local[j]; }
}

__global__ void scatter_kernel(const int* __restrict__ batch, int* __restrict__ runoff,
                               int* __restrict__ perm, int* __restrict__ sbat) {
    int i = blockIdx.x * 256 + threadIdx.x;
    if (i < NNODES) {
        int g = batch[i];
        int p = atomicAdd(&runoff[g], 1);
        perm[p] = i;
        sbat[p] = g;
    }
}

// ---------------- phase 1: per-node MLP + LN (R0 structure) -----------------
// mode 0: atomic scatter to agg (R0 fallback). mode 1: coalesced f16 store to h3.
__global__ __launch_bounds__(256, 2) void node_kernel(
    const float* __restrict__ x, const float* __restrict__ u, const int* __restrict__ batch,
    const _Float16* __restrict__ w1T, const _Float16* __restrict__ w2T,
    const _Float16* __restrict__ w3T,
    const float* __restrict__ b1, const float* __restrict__ b2, const float* __restrict__ b3,
    const float* __restrict__ lng, const float* __restrict__ lnb,
    float* __restrict__ agg, _Float16* __restrict__ h3, int mode)
{
    __shared__ __align__(16) _Float16 hA[ROWS * LDH];
    __shared__ int sBatch[ROWS];

    const int tid = threadIdx.x;
    const int rowbase = blockIdx.x * ROWS;
    const int wave = tid >> 6;
    const int lane = tid & 63;
    const int q = lane >> 4;      // quad (k-block / row-block selector)
    const int l16 = lane & 15;

    // stage batch indices
    for (int r = tid; r < ROWS; r += 256) {
        int gr = rowbase + r;
        sBatch[r] = (gr < NNODES) ? batch[gr] : 0;
    }
    __syncthreads();

    // stage h0 = concat(x, u[batch]) as f16
    for (int i = tid; i < ROWS * 16; i += 256) {
        int r = i >> 4, c4 = (i & 15) << 2;
        int gr = rowbase + r;
        float4 vx = make_float4(0.f, 0.f, 0.f, 0.f);
        if (gr < NNODES) vx = *(const float4*)(x + (size_t)gr * 64 + c4);
        _Float16* p = &hA[r * LDH + c4];
        p[0] = (_Float16)vx.x; p[1] = (_Float16)vx.y;
        p[2] = (_Float16)vx.z; p[3] = (_Float16)vx.w;
        int g = sBatch[r];
        float4 vu = *(const float4*)(u + (size_t)g * 64 + c4);
        _Float16* p2 = &hA[r * LDH + 64 + c4];
        p2[0] = (_Float16)vu.x; p2[1] = (_Float16)vu.y;
        p2[2] = (_Float16)vu.z; p2[3] = (_Float16)vu.w;
    }
    __syncthreads();

    // ---- layers 1 & 2: 128x128, relu, in-place in hA ----
    const int rowg = (wave >> 1) * 64;
    const int colg = (wave & 1) * 64;
    for (int layer = 0; layer < 2; ++layer) {
        const _Float16* wT = layer ? w2T : w1T;
        const float* bias = layer ? b2 : b1;
        floatx4 acc[4][4];
        #pragma unroll
        for (int ct = 0; ct < 4; ++ct) {
            float bv = bias[colg + ct * 16 + l16];
            #pragma unroll
            for (int rt = 0; rt < 4; ++rt) acc[rt][ct] = (floatx4){bv, bv, bv, bv};
        }
        half8 bfr[4][4];
        #pragma unroll
        for (int ks = 0; ks < 4; ++ks)
            #pragma unroll
            for (int ct = 0; ct < 4; ++ct)
                bfr[ks][ct] = *(const half8*)(wT + (colg + ct * 16 + l16) * 128 + ks * 32 + q * 8);
        #pragma unroll
        for (int ks = 0; ks < 4; ++ks) {
            half8 af[4];
            #pragma unroll
            for (int rt = 0; rt < 4; ++rt)
                af[rt] = *(const half8*)(&hA[(rowg + rt * 16 + l16) * LDH + ks * 32 + q * 8]);
            #pragma unroll
            for (int rt = 0; rt < 4; ++rt)
                #pragma unroll
                for (int ct = 0; ct < 4; ++ct)
                    acc[rt][ct] = __builtin_amdgcn_mfma_f32_16x16x32_f16(
                        af[rt], bfr[ks][ct], acc[rt][ct], 0, 0, 0);
        }
        __syncthreads();   // all reads of hA complete
        #pragma unroll
        for (int rt = 0; rt < 4; ++rt)
            #pragma unroll
            for (int ct = 0; ct < 4; ++ct)
                #pragma unroll
                for (int j = 0; j < 4; ++j) {
                    float v = acc[rt][ct][j];
                    v = v > 0.f ? v : 0.f;
                    hA[(rowg + rt * 16 + q * 4 + j) * LDH + colg + ct * 16 + l16] = (_Float16)v;
                }
        __syncthreads();   // writes visible
    }

    // ---- layer 3: 128x64 + LN ----
    {
        const int rowg3 = wave * 32;   // 4 waves x 32 rows (wave-private rows)
        floatx4 acc[2][4];
        #pragma unroll
        for (int ct = 0; ct < 4; ++ct) {
            float bv = b3[ct * 16 + l16];
            acc[0][ct] = (floatx4){bv, bv, bv, bv};
            acc[1][ct] = (floatx4){bv, bv, bv, bv};
        }
        half8 bfr[4][4];
        #pragma unroll
        for (int ks = 0; ks < 4; ++ks)
            #pragma unroll
            for (int ct = 0; ct < 4; ++ct)
                bfr[ks][ct] = *(const half8*)(w3T + (ct * 16 + l16) * 128 + ks * 32 + q * 8);
        #pragma unroll
        for (int ks = 0; ks < 4; ++ks) {
            half8 af[2];
            #pragma unroll
            for (int rt = 0; rt < 2; ++rt)
                af[rt] = *(const half8*)(&hA[(rowg3 + rt * 16 + l16) * LDH + ks * 32 + q * 8]);
            #pragma unroll
            for (int rt = 0; rt < 2; ++rt)
                #pragma unroll
                for (int ct = 0; ct < 4; ++ct)
                    acc[rt][ct] = __builtin_amdgcn_mfma_f32_16x16x32_f16(
                        af[rt], bfr[ks][ct], acc[rt][ct], 0, 0, 0);
        }
        float gct[4], bct[4];
        #pragma unroll
        for (int ct = 0; ct < 4; ++ct) {
            gct[ct] = lng[ct * 16 + l16];
            bct[ct] = lnb[ct * 16 + l16];
        }
        #pragma unroll
        for (int rt = 0; rt < 2; ++rt)
            #pragma unroll
            for (int j = 0; j < 4; ++j) {
                int rloc = rowg3 + rt * 16 + q * 4 + j;   // quad-uniform row
                float v0 = acc[rt][0][j], v1 = acc[rt][1][j];
                float v2 = acc[rt][2][j], v3 = acc[rt][3][j];
                float s = v0 + v1 + v2 + v3;
                float ss = v0 * v0 + v1 * v1 + v2 * v2 + v3 * v3;
                #pragma unroll
                for (int m = 1; m < 16; m <<= 1) {
                    s += __shfl_xor(s, m, 16);
                    ss += __shfl_xor(ss, m, 16);
                }
                float mean = s * (1.f / 64.f);
                float var = ss * (1.f / 64.f) - mean * mean;
                float rstd = rsqrtf(var + 1e-5f);
                float o0 = (v0 - mean) * rstd * gct[0] + bct[0];
                float o1 = (v1 - mean) * rstd * gct[1] + bct[1];
                float o2 = (v2 - mean) * rstd * gct[2] + bct[2];
                float o3 = (v3 - mean) * rstd * gct[3] + bct[3];
                if (mode == 0) {
                    if (rowbase + rloc < NNODES) {
                        float* dst = agg + (size_t)sBatch[rloc] * 64;
                        unsafeAtomicAdd(dst + 0 + l16,  o0);
                        unsafeAtomicAdd(dst + 16 + l16, o1);
                        unsafeAtomicAdd(dst + 32 + l16, o2);
                        unsafeAtomicAdd(dst + 48 + l16, o3);
                    }
                } else {
                    // write LN output into hA cols 0..63 (wave-private rows,
                    // in-order DS pipe: no barrier needed before copy-out)
                    _Float16* dr = &hA[rloc * LDH];
                    dr[0 + l16]  = (_Float16)o0;
                    dr[16 + l16] = (_Float16)o1;
                    dr[32 + l16] = (_Float16)o2;
                    dr[48 + l16] = (_Float16)o3;
                }
            }
        if (mode != 0) {
            // coalesced copy-out: wave copies its own 32 rows (32x64 f16 = 4KB)
            // lane l: row = l>>1, half = l&1 -> 32 f16 per lane (4 x half8)
            int r = rowg3 + (lane >> 1);
            int half = lane & 1;
            int gr = rowbase + r;
            if (gr < NNODES) {
                const half8* src = (const half8*)(&hA[r * LDH + half * 32]);
                half8 a0 = src[0];
                half8 a1 = src[1];
                half8 a2 = src[2];
                half8 a3 = src[3];
                half8* dst = (half8*)(h3 + (size_t)gr * 64 + half * 32);
                dst[0] = a0;
                dst[1] = a1;
                dst[2] = a2;
                dst[3] = a3;
            }
        }
    }
}

// ---------------- aggregation: sorted-order run-accumulate ------------------
// one wave per 128 sorted rows; lane = column; flush at graph boundaries.
__global__ __launch_bounds__(256, 8) void agg_kernel(
    const _Float16* __restrict__ h3, const int* __restrict__ perm,
    const int* __restrict__ sbat, float* __restrict__ agg)
{
    const int wave = threadIdx.x >> 6, lane = threadIdx.x & 63;
    const int wid = blockIdx.x * 4 + wave;
    const int start = wid * 128;
    if (start >= NNODES) return;
    const int end = min(start + 128, NNODES);

    int gcur = sbat[start];
    float acc = 0.f;
    for (int j = start; j < end; j += 4) {
        int4 pm = *(const int4*)(perm + j);
        int4 gb = *(const int4*)(sbat + j);
        // issue all 4 row loads up-front (independent, pipelined)
        float v0 = (float)h3[(size_t)pm.x * 64 + lane];
        float v1 = (float)h3[(size_t)pm.y * 64 + lane];
        float v2 = (float)h3[(size_t)pm.z * 64 + lane];
        float v3 = (float)h3[(size_t)pm.w * 64 + lane];
        if (gb.x != gcur) { unsafeAtomicAdd(agg + (size_t)gcur * 64 + lane, acc); acc = 0.f; gcur = gb.x; }
        acc += v0;
        if (gb.y != gcur) { unsafeAtomicAdd(agg + (size_t)gcur * 64 + lane, acc); acc = 0.f; gcur = gb.y; }
        acc += v1;
        if (gb.z != gcur) { unsafeAtomicAdd(agg + (size_t)gcur * 64 + lane, acc); acc = 0.f; gcur = gb.z; }
        acc += v2;
        if (gb.w != gcur) { unsafeAtomicAdd(agg + (size_t)gcur * 64 + lane, acc); acc = 0.f; gcur = gb.w; }
        acc += v3;
    }
    unsafeAtomicAdd(agg + (size_t)gcur * 64 + lane, acc);
}

// ---------------- phase 2: per-graph MLP, f16 MFMA (32 blocks x 128 rows) ---
__global__ __launch_bounds__(256, 2) void graph2_kernel(
    const float* __restrict__ u,
    const _Float16* __restrict__ w4T, const _Float16* __restrict__ w5T,
    const _Float16* __restrict__ w6T,
    const float* __restrict__ b4, const float* __restrict__ b5, const float* __restrict__ b6,
    const float* __restrict__ lng, const float* __restrict__ lnb,
    float* __restrict__ out)   // out holds agg on entry; rows block-exclusive
{
    __shared__ __align__(16) _Float16 hA[128 * LDH];

    const int tid = threadIdx.x;
    const int rowbase = blockIdx.x * 128;
    const int wave = tid >> 6;
    const int lane = tid & 63;
    const int q = lane >> 4;
    const int l16 = lane & 15;

    // stage g0 = concat(agg, u) as f16
    for (int i = tid; i < 128 * 16; i += 256) {
        int r = i >> 4, c4 = (i & 15) << 2;
        int g = rowbase + r;
        float4 va = *(const float4*)(out + (size_t)g * 64 + c4);
        _Float16* p = &hA[r * LDH + c4];
        p[0] = (_Float16)va.x; p[1] = (_Float16)va.y;
        p[2] = (_Float16)va.z; p[3] = (_Float16)va.w;
        float4 vu = *(const float4*)(u + (size_t)g * 64 + c4);
        _Float16* p2 = &hA[r * LDH + 64 + c4];
        p2[0] = (_Float16)vu.x; p2[1] = (_Float16)vu.y;
        p2[2] = (_Float16)vu.z; p2[3] = (_Float16)vu.w;
    }
    __syncthreads();

    // ---- layers 4 & 5: 128x128, relu, in-place ----
    const int rowg = (wave >> 1) * 64;
    const int colg = (wave & 1) * 64;
    for (int layer = 0; layer < 2; ++layer) {
        const _Float16* wT = layer ? w5T : w4T;
        const float* bias = layer ? b5 : b4;
        floatx4 acc[4][4];
        #pragma unroll
        for (int ct = 0; ct < 4; ++ct) {
            float bv = bias[colg + ct * 16 + l16];
            #pragma unroll
            for (int rt = 0; rt < 4; ++rt) acc[rt][ct] = (floatx4){bv, bv, bv, bv};
        }
        half8 bfr[4][4];
        #pragma unroll
        for (int ks = 0; ks < 4; ++ks)
            #pragma unroll
            for (int ct = 0; ct < 4; ++ct)
                bfr[ks][ct] = *(const half8*)(wT + (colg + ct * 16 + l16) * 128 + ks * 32 + q * 8);
        #pragma unroll
        for (int ks = 0; ks < 4; ++ks) {
            half8 af[4];
            #pragma unroll
            for (int rt = 0; rt < 4; ++rt)
                af[rt] = *(const half8*)(&hA[(rowg + rt * 16 + l16) * LDH + ks * 32 + q * 8]);
            #pragma unroll
            for (int rt = 0; rt < 4; ++rt)
                #pragma unroll
                for (int ct = 0; ct < 4; ++ct)
                    acc[rt][ct] = __builtin_amdgcn_mfma_f32_16x16x32_f16(
                        af[rt], bfr[ks][ct], acc[rt][ct], 0, 0, 0);
        }
        __syncthreads();
        #pragma unroll
        for (int rt = 0; rt < 4; ++rt)
            #pragma unroll
            for (int ct = 0; ct < 4; ++ct)
                #pragma unroll
                for (int j = 0; j < 4; ++j) {
                    float v = acc[rt][ct][j];
                    v = v > 0.f ? v : 0.f;
                    hA[(rowg + rt * 16 + q * 4 + j) * LDH + colg + ct * 16 + l16] = (_Float16)v;
                }
        __syncthreads();
    }

    // ---- layer 6: 128x64 + LN + residual + store ----
    {
        const int rowg3 = wave * 32;
        floatx4 acc[2][4];
        #pragma unroll
        for (int ct = 0; ct < 4; ++ct) {
            float bv = b6[ct * 16 + l16];
            acc[0][ct] = (floatx4){bv, bv, bv, bv};
            acc[1][ct] = (floatx4){bv, bv, bv, bv};
        }
        half8 bfr[4][4];
        #pragma unroll
        for (int ks = 0; ks < 4; ++ks)
            #pragma unroll
            for (int ct = 0; ct < 4; ++ct)
                bfr[ks][ct] = *(const half8*)(w6T + (ct * 16 + l16) * 128 + ks * 32 + q * 8);
        #pragma unroll
        for (int ks = 0; ks < 4; ++ks) {
            half8 af[2];
            #pragma unroll
            for (int rt = 0; rt < 2; ++rt)
                af[rt] = *(const half8*)(&hA[(rowg3 + rt * 16 + l16) * LDH + ks * 32 + q * 8]);
            #pragma unroll
            for (int rt = 0; rt < 2; ++rt)
                #pragma unroll
                for (int ct = 0; ct < 4; ++ct)
                    acc[rt][ct] = __builtin_amdgcn_mfma_f32_16x16x32_f16(
                        af[rt], bfr[ks][ct], acc[rt][ct], 0, 0, 0);
        }
        float gct[4], bct[4];
        #pragma unroll
        for (int ct = 0; ct < 4; ++ct) {
            gct[ct] = lng[ct * 16 + l16];
            bct[ct] = lnb[ct * 16 + l16];
        }
        #pragma unroll
        for (int rt = 0; rt < 2; ++rt)
            #pragma unroll
            for (int j = 0; j < 4; ++j) {
                int rloc = rowg3 + rt * 16 + q * 4 + j;
                size_t g = (size_t)(rowbase + rloc);
                float v0 = acc[rt][0][j], v1 = acc[rt][1][j];
                float v2 = acc[rt][2][j], v3 = acc[rt][3][j];
                float s = v0 + v1 + v2 + v3;
                float ss = v0 * v0 + v1 * v1 + v2 * v2 + v3 * v3;
                #pragma unroll
                for (int m = 1; m < 16; m <<= 1) {
                    s += __shfl_xor(s, m, 16);
                    ss += __shfl_xor(ss, m, 16);
                }
                float mean = s * (1.f / 64.f);
                float var = ss * (1.f / 64.f) - mean * mean;
                float rstd = rsqrtf(var + 1e-5f);
                out[g * 64 + 0 + l16]  = (v0 - mean) * rstd * gct[0] + bct[0] + u[g * 64 + 0 + l16];
                out[g * 64 + 16 + l16] = (v1 - mean) * rstd * gct[1] + bct[1] + u[g * 64 + 16 + l16];
                out[g * 64 + 32 + l16] = (v2 - mean) * rstd * gct[2] + bct[2] + u[g * 64 + 32 + l16];
                out[g * 64 + 48 + l16] = (v3 - mean) * rstd * gct[3] + bct[3] + u[g * 64 + 48 + l16];
            }
    }
}

extern "C" void kernel_launch(void* const* d_in, const int* in_sizes, int n_in,
                              void* d_out, int out_size, void* d_ws, size_t ws_size,
                              hipStream_t stream) {
    const float* x   = (const float*)d_in[0];
    const float* u   = (const float*)d_in[1];
    const int*   bt  = (const int*)d_in[2];
    const float* w1  = (const float*)d_in[3];
    const float* b1  = (const float*)d_in[4];
    const float* w2  = (const float*)d_in[5];
    const float* b2  = (const float*)d_in[6];
    const float* w3  = (const float*)d_in[7];
    const float* b3  = (const float*)d_in[8];
    const float* lng = (const float*)d_in[9];
    const float* lnb = (const float*)d_in[10];
    const float* w4  = (const float*)d_in[11];
    const float* b4  = (const float*)d_in[12];
    const float* w5  = (const float*)d_in[13];
    const float* b5  = (const float*)d_in[14];
    const float* w6  = (const float*)d_in[15];
    const float* b6  = (const float*)d_in[16];
    const float* g2  = (const float*)d_in[17];
    const float* bb2 = (const float*)d_in[18];
    float* out = (float*)d_out;

    // workspace layout
    _Float16* w1T = (_Float16*)d_ws;
    _Float16* w2T = w1T + 128 * 128;
    _Float16* w3T = w2T + 128 * 128;
    _Float16* w4T = w3T + 64 * 128;
    _Float16* w5T = w4T + 128 * 128;
    _Float16* w6T = w5T + 128 * 128;
    int* cnt    = (int*)(w6T + 64 * 128);
    int* runoff = cnt + NGRAPHS;
    int* perm   = runoff + NGRAPHS;
    int* sbat   = perm + NNODES;
    _Float16* h3 = (_Float16*)(sbat + NNODES);
    size_t needed = (size_t)((char*)(h3 + (size_t)NNODES * 64) - (char*)d_ws);
    const int sorted_mode = (ws_size >= needed) ? 1 : 0;

    hipMemsetAsync(d_out, 0, (size_t)NGRAPHS * 64 * sizeof(float), stream);
    prep_kernel<<<64, 256, 0, stream>>>(w1, w2, w3, w4, w5, w6,
                                        w1T, w2T, w3T, w4T, w5T, w6T);
    if (sorted_mode) {
        hipMemsetAsync(cnt, 0, (size_t)NGRAPHS * sizeof(int), stream);
        hist_kernel<<<64, 256, 0, stream>>>(bt, cnt);
        scan_kernel<<<1, 256, 0, stream>>>(cnt, runoff);
        scatter_kernel<<<(NNODES + 255) / 256, 256, 0, stream>>>(bt, runoff, perm, sbat);
    }
    node_kernel<<<(NNODES + ROWS - 1) / ROWS, 256, 0, stream>>>(
        x, u, bt, w1T, w2T, w3T, b1, b2, b3, lng, lnb, out, h3, sorted_mode);
    if (sorted_mode) {
        // 3907 waves x 128 sorted rows, 4 waves/block
        agg_kernel<<<(NNODES / 128 + 4) / 4, 256, 0, stream>>>(h3, perm, sbat, out);
    }
    graph2_kernel<<<NGRAPHS / 128, 256, 0, stream>>>(
        u, w4T, w5T, w6T, b4, b5, b6, g2, bb2, out);
}

// Round 8
// 401.651 us; speedup vs baseline: 1.4754x; 1.0594x over previous
//
#include <hip/hip_runtime.h>
#include <hip/hip_bf16.h>
#include <stdint.h>

// GraphNet global block, MI355X.
// R7/R8: best measured composition. Ledger from R0/R2/R6:
//   node+atomics=222us (R0) | node-no-atomics=167us (R6) | sort+h3+agg stack
//   ~240us (R2/R6) | old graph_kernel ~165us (R0) | MFMA graph2 ~10us.
// The sort stack costs 240 to save 55 -> drop it. Keep R0 node (atomic tail,
// batched weight prefetch, coalesced reads) + fast MFMA graph2. Predicted
// total ~255-270us. agg buffer aliases d_out (graph2 reads before overwrite).
// R8: identical resubmit (R7 bench failed: container infra error, no verdict).

#define NNODES 500000
#define NGRAPHS 4096
#define ROWS 128      // node rows per block
#define LDH 136       // padded f16 row stride (272 B: 16B-aligned, conflict-free)

typedef __attribute__((ext_vector_type(8))) _Float16 half8;
typedef __attribute__((ext_vector_type(4))) float floatx4;

// ---------------- prep: transpose all six weights to f16 [N][K] -------------
__global__ void prep_kernel(const float* __restrict__ w1, const float* __restrict__ w2,
                            const float* __restrict__ w3, const float* __restrict__ w4,
                            const float* __restrict__ w5, const float* __restrict__ w6,
                            _Float16* __restrict__ w1T, _Float16* __restrict__ w2T,
                            _Float16* __restrict__ w3T, _Float16* __restrict__ w4T,
                            _Float16* __restrict__ w5T, _Float16* __restrict__ w6T) {
    int i = blockIdx.x * 256 + threadIdx.x;   // 0..16383
    if (i < 128 * 128) {
        int n = i >> 7, k = i & 127;
        w1T[i] = (_Float16)w1[k * 128 + n];
        w2T[i] = (_Float16)w2[k * 128 + n];
        w4T[i] = (_Float16)w4[k * 128 + n];
        w5T[i] = (_Float16)w5[k * 128 + n];
    }
    if (i < 64 * 128) {
        int n = i >> 7, k = i & 127;
        w3T[i] = (_Float16)w3[k * 64 + n];
        w6T[i] = (_Float16)w6[k * 64 + n];
    }
}

// ---------------- phase 1: per-node MLP + LN + atomic scatter (R0) ----------
__global__ __launch_bounds__(256, 2) void node_kernel(
    const float* __restrict__ x, const float* __restrict__ u, const int* __restrict__ batch,
    const _Float16* __restrict__ w1T, const _Float16* __restrict__ w2T,
    const _Float16* __restrict__ w3T,
    const float* __restrict__ b1, const float* __restrict__ b2, const float* __restrict__ b3,
    const float* __restrict__ lng, const float* __restrict__ lnb,
    float* __restrict__ agg)
{
    __shared__ __align__(16) _Float16 hA[ROWS * LDH];
    __shared__ int sBatch[ROWS];

    const int tid = threadIdx.x;
    const int rowbase = blockIdx.x * ROWS;
    const int wave = tid >> 6;
    const int lane = tid & 63;
    const int q = lane >> 4;      // quad (k-block / row-block selector)
    const int l16 = lane & 15;

    // stage batch indices
    for (int r = tid; r < ROWS; r += 256) {
        int gr = rowbase + r;
        sBatch[r] = (gr < NNODES) ? batch[gr] : 0;
    }
    __syncthreads();

    // stage h0 = concat(x, u[batch]) as f16
    for (int i = tid; i < ROWS * 16; i += 256) {
        int r = i >> 4, c4 = (i & 15) << 2;
        int gr = rowbase + r;
        float4 vx = make_float4(0.f, 0.f, 0.f, 0.f);
        if (gr < NNODES) vx = *(const float4*)(x + (size_t)gr * 64 + c4);
        _Float16* p = &hA[r * LDH + c4];
        p[0] = (_Float16)vx.x; p[1] = (_Float16)vx.y;
        p[2] = (_Float16)vx.z; p[3] = (_Float16)vx.w;
        int g = sBatch[r];
        float4 vu = *(const float4*)(u + (size_t)g * 64 + c4);
        _Float16* p2 = &hA[r * LDH + 64 + c4];
        p2[0] = (_Float16)vu.x; p2[1] = (_Float16)vu.y;
        p2[2] = (_Float16)vu.z; p2[3] = (_Float16)vu.w;
    }
    __syncthreads();

    // ---- layers 1 & 2: 128x128, relu, in-place in hA ----
    const int rowg = (wave >> 1) * 64;
    const int colg = (wave & 1) * 64;
    for (int layer = 0; layer < 2; ++layer) {
        const _Float16* wT = layer ? w2T : w1T;
        const float* bias = layer ? b2 : b1;
        floatx4 acc[4][4];
        #pragma unroll
        for (int ct = 0; ct < 4; ++ct) {
            float bv = bias[colg + ct * 16 + l16];
            #pragma unroll
            for (int rt = 0; rt < 4; ++rt) acc[rt][ct] = (floatx4){bv, bv, bv, bv};
        }
        half8 bfr[4][4];
        #pragma unroll
        for (int ks = 0; ks < 4; ++ks)
            #pragma unroll
            for (int ct = 0; ct < 4; ++ct)
                bfr[ks][ct] = *(const half8*)(wT + (colg + ct * 16 + l16) * 128 + ks * 32 + q * 8);
        #pragma unroll
        for (int ks = 0; ks < 4; ++ks) {
            half8 af[4];
            #pragma unroll
            for (int rt = 0; rt < 4; ++rt)
                af[rt] = *(const half8*)(&hA[(rowg + rt * 16 + l16) * LDH + ks * 32 + q * 8]);
            #pragma unroll
            for (int rt = 0; rt < 4; ++rt)
                #pragma unroll
                for (int ct = 0; ct < 4; ++ct)
                    acc[rt][ct] = __builtin_amdgcn_mfma_f32_16x16x32_f16(
                        af[rt], bfr[ks][ct], acc[rt][ct], 0, 0, 0);
        }
        __syncthreads();   // all reads of hA complete
        #pragma unroll
        for (int rt = 0; rt < 4; ++rt)
            #pragma unroll
            for (int ct = 0; ct < 4; ++ct)
                #pragma unroll
                for (int j = 0; j < 4; ++j) {
                    float v = acc[rt][ct][j];
                    v = v > 0.f ? v : 0.f;
                    hA[(rowg + rt * 16 + q * 4 + j) * LDH + colg + ct * 16 + l16] = (_Float16)v;
                }
        __syncthreads();   // writes visible
    }

    // ---- layer 3: 128x64 + LN + atomic scatter ----
    {
        const int rowg3 = wave * 32;   // 4 waves x 32 rows
        floatx4 acc[2][4];
        #pragma unroll
        for (int ct = 0; ct < 4; ++ct) {
            float bv = b3[ct * 16 + l16];
            acc[0][ct] = (floatx4){bv, bv, bv, bv};
            acc[1][ct] = (floatx4){bv, bv, bv, bv};
        }
        half8 bfr[4][4];
        #pragma unroll
        for (int ks = 0; ks < 4; ++ks)
            #pragma unroll
            for (int ct = 0; ct < 4; ++ct)
                bfr[ks][ct] = *(const half8*)(w3T + (ct * 16 + l16) * 128 + ks * 32 + q * 8);
        #pragma unroll
        for (int ks = 0; ks < 4; ++ks) {
            half8 af[2];
            #pragma unroll
            for (int rt = 0; rt < 2; ++rt)
                af[rt] = *(const half8*)(&hA[(rowg3 + rt * 16 + l16) * LDH + ks * 32 + q * 8]);
            #pragma unroll
            for (int rt = 0; rt < 2; ++rt)
                #pragma unroll
                for (int ct = 0; ct < 4; ++ct)
                    acc[rt][ct] = __builtin_amdgcn_mfma_f32_16x16x32_f16(
                        af[rt], bfr[ks][ct], acc[rt][ct], 0, 0, 0);
        }
        float gct[4], bct[4];
        #pragma unroll
        for (int ct = 0; ct < 4; ++ct) {
            gct[ct] = lng[ct * 16 + l16];
            bct[ct] = lnb[ct * 16 + l16];
        }
        #pragma unroll
        for (int rt = 0; rt < 2; ++rt)
            #pragma unroll
            for (int j = 0; j < 4; ++j) {
                int rloc = rowg3 + rt * 16 + q * 4 + j;   // quad-uniform row
                float v0 = acc[rt][0][j], v1 = acc[rt][1][j];
                float v2 = acc[rt][2][j], v3 = acc[rt][3][j];
                float s = v0 + v1 + v2 + v3;
                float ss = v0 * v0 + v1 * v1 + v2 * v2 + v3 * v3;
                #pragma unroll
                for (int m = 1; m < 16; m <<= 1) {
                    s += __shfl_xor(s, m, 16);
                    ss += __shfl_xor(ss, m, 16);
                }
                float mean = s * (1.f / 64.f);
                float var = ss * (1.f / 64.f) - mean * mean;
                float rstd = rsqrtf(var + 1e-5f);
                if (rowbase + rloc < NNODES) {
                    float* dst = agg + (size_t)sBatch[rloc] * 64;
                    unsafeAtomicAdd(dst + 0 + l16,  (v0 - mean) * rstd * gct[0] + bct[0]);
                    unsafeAtomicAdd(dst + 16 + l16, (v1 - mean) * rstd * gct[1] + bct[1]);
                    unsafeAtomicAdd(dst + 32 + l16, (v2 - mean) * rstd * gct[2] + bct[2]);
                    unsafeAtomicAdd(dst + 48 + l16, (v3 - mean) * rstd * gct[3] + bct[3]);
                }
            }
    }
}

// ---------------- phase 2: per-graph MLP, f16 MFMA (32 blocks x 128 rows) ---
__global__ __launch_bounds__(256, 2) void graph2_kernel(
    const float* __restrict__ u,
    const _Float16* __restrict__ w4T, const _Float16* __restrict__ w5T,
    const _Float16* __restrict__ w6T,
    const float* __restrict__ b4, const float* __restrict__ b5, const float* __restrict__ b6,
    const float* __restrict__ lng, const float* __restrict__ lnb,
    float* __restrict__ out)   // out holds agg on entry; rows block-exclusive
{
    __shared__ __align__(16) _Float16 hA[128 * LDH];

    const int tid = threadIdx.x;
    const int rowbase = blockIdx.x * 128;
    const int wave = tid >> 6;
    const int lane = tid & 63;
    const int q = lane >> 4;
    const int l16 = lane & 15;

    // stage g0 = concat(agg, u) as f16
    for (int i = tid; i < 128 * 16; i += 256) {
        int r = i >> 4, c4 = (i & 15) << 2;
        int g = rowbase + r;
        float4 va = *(const float4*)(out + (size_t)g * 64 + c4);
        _Float16* p = &hA[r * LDH + c4];
        p[0] = (_Float16)va.x; p[1] = (_Float16)va.y;
        p[2] = (_Float16)va.z; p[3] = (_Float16)va.w;
        float4 vu = *(const float4*)(u + (size_t)g * 64 + c4);
        _Float16* p2 = &hA[r * LDH + 64 + c4];
        p2[0] = (_Float16)vu.x; p2[1] = (_Float16)vu.y;
        p2[2] = (_Float16)vu.z; p2[3] = (_Float16)vu.w;
    }
    __syncthreads();

    // ---- layers 4 & 5: 128x128, relu, in-place ----
    const int rowg = (wave >> 1) * 64;
    const int colg = (wave & 1) * 64;
    for (int layer = 0; layer < 2; ++layer) {
        const _Float16* wT = layer ? w5T : w4T;
        const float* bias = layer ? b5 : b4;
        floatx4 acc[4][4];
        #pragma unroll
        for (int ct = 0; ct < 4; ++ct) {
            float bv = bias[colg + ct * 16 + l16];
            #pragma unroll
            for (int rt = 0; rt < 4; ++rt) acc[rt][ct] = (floatx4){bv, bv, bv, bv};
        }
        half8 bfr[4][4];
        #pragma unroll
        for (int ks = 0; ks < 4; ++ks)
            #pragma unroll
            for (int ct = 0; ct < 4; ++ct)
                bfr[ks][ct] = *(const half8*)(wT + (colg + ct * 16 + l16) * 128 + ks * 32 + q * 8);
        #pragma unroll
        for (int ks = 0; ks < 4; ++ks) {
            half8 af[4];
            #pragma unroll
            for (int rt = 0; rt < 4; ++rt)
                af[rt] = *(const half8*)(&hA[(rowg + rt * 16 + l16) * LDH + ks * 32 + q * 8]);
            #pragma unroll
            for (int rt = 0; rt < 4; ++rt)
                #pragma unroll
                for (int ct = 0; ct < 4; ++ct)
                    acc[rt][ct] = __builtin_amdgcn_mfma_f32_16x16x32_f16(
                        af[rt], bfr[ks][ct], acc[rt][ct], 0, 0, 0);
        }
        __syncthreads();
        #pragma unroll
        for (int rt = 0; rt < 4; ++rt)
            #pragma unroll
            for (int ct = 0; ct < 4; ++ct)
                #pragma unroll
                for (int j = 0; j < 4; ++j) {
                    float v = acc[rt][ct][j];
                    v = v > 0.f ? v : 0.f;
                    hA[(rowg + rt * 16 + q * 4 + j) * LDH + colg + ct * 16 + l16] = (_Float16)v;
                }
        __syncthreads();
    }

    // ---- layer 6: 128x64 + LN + residual + store ----
    {
        const int rowg3 = wave * 32;
        floatx4 acc[2][4];
        #pragma unroll
        for (int ct = 0; ct < 4; ++ct) {
            float bv = b6[ct * 16 + l16];
            acc[0][ct] = (floatx4){bv, bv, bv, bv};
            acc[1][ct] = (floatx4){bv, bv, bv, bv};
        }
        half8 bfr[4][4];
        #pragma unroll
        for (int ks = 0; ks < 4; ++ks)
            #pragma unroll
            for (int ct = 0; ct < 4; ++ct)
                bfr[ks][ct] = *(const half8*)(w6T + (ct * 16 + l16) * 128 + ks * 32 + q * 8);
        #pragma unroll
        for (int ks = 0; ks < 4; ++ks) {
            half8 af[2];
            #pragma unroll
            for (int rt = 0; rt < 2; ++rt)
                af[rt] = *(const half8*)(&hA[(rowg3 + rt * 16 + l16) * LDH + ks * 32 + q * 8]);
            #pragma unroll
            for (int rt = 0; rt < 2; ++rt)
                #pragma unroll
                for (int ct = 0; ct < 4; ++ct)
                    acc[rt][ct] = __builtin_amdgcn_mfma_f32_16x16x32_f16(
                        af[rt], bfr[ks][ct], acc[rt][ct], 0, 0, 0);
        }
        float gct[4], bct[4];
        #pragma unroll
        for (int ct = 0; ct < 4; ++ct) {
            gct[ct] = lng[ct * 16 + l16];
            bct[ct] = lnb[ct * 16 + l16];
        }
        #pragma unroll
        for (int rt = 0; rt < 2; ++rt)
            #pragma unroll
            for (int j = 0; j < 4; ++j) {
                int rloc = rowg3 + rt * 16 + q * 4 + j;
                size_t g = (size_t)(rowbase + rloc);
                float v0 = acc[rt][0][j], v1 = acc[rt][1][j];
                float v2 = acc[rt][2][j], v3 = acc[rt][3][j];
                float s = v0 + v1 + v2 + v3;
                float ss = v0 * v0 + v1 * v1 + v2 * v2 + v3 * v3;
                #pragma unroll
                for (int m = 1; m < 16; m <<= 1) {
                    s += __shfl_xor(s, m, 16);
                    ss += __shfl_xor(ss, m, 16);
                }
                float mean = s * (1.f / 64.f);
                float var = ss * (1.f / 64.f) - mean * mean;
                float rstd = rsqrtf(var + 1e-5f);
                out[g * 64 + 0 + l16]  = (v0 - mean) * rstd * gct[0] + bct[0] + u[g * 64 + 0 + l16];
                out[g * 64 + 16 + l16] = (v1 - mean) * rstd * gct[1] + bct[1] + u[g * 64 + 16 + l16];
                out[g * 64 + 32 + l16] = (v2 - mean) * rstd * gct[2] + bct[2] + u[g * 64 + 32 + l16];
                out[g * 64 + 48 + l16] = (v3 - mean) * rstd * gct[3] + bct[3] + u[g * 64 + 48 + l16];
            }
    }
}

extern "C" void kernel_launch(void* const* d_in, const int* in_sizes, int n_in,
                              void* d_out, int out_size, void* d_ws, size_t ws_size,
                              hipStream_t stream) {
    const float* x   = (const float*)d_in[0];
    const float* u   = (const float*)d_in[1];
    const int*   bt  = (const int*)d_in[2];
    const float* w1  = (const float*)d_in[3];
    const float* b1  = (const float*)d_in[4];
    const float* w2  = (const float*)d_in[5];
    const float* b2  = (const float*)d_in[6];
    const float* w3  = (const float*)d_in[7];
    const float* b3  = (const float*)d_in[8];
    const float* lng = (const float*)d_in[9];
    const float* lnb = (const float*)d_in[10];
    const float* w4  = (const float*)d_in[11];
    const float* b4  = (const float*)d_in[12];
    const float* w5  = (const float*)d_in[13];
    const float* b5  = (const float*)d_in[14];
    const float* w6  = (const float*)d_in[15];
    const float* b6  = (const float*)d_in[16];
    const float* g2  = (const float*)d_in[17];
    const float* bb2 = (const float*)d_in[18];
    float* out = (float*)d_out;

    // workspace: 6 f16 weight transposes (160 KB)
    _Float16* w1T = (_Float16*)d_ws;
    _Float16* w2T = w1T + 128 * 128;
    _Float16* w3T = w2T + 128 * 128;
    _Float16* w4T = w3T + 64 * 128;
    _Float16* w5T = w4T + 128 * 128;
    _Float16* w6T = w5T + 128 * 128;

    hipMemsetAsync(d_out, 0, (size_t)NGRAPHS * 64 * sizeof(float), stream);
    prep_kernel<<<64, 256, 0, stream>>>(w1, w2, w3, w4, w5, w6,
                                        w1T, w2T, w3T, w4T, w5T, w6T);
    node_kernel<<<(NNODES + ROWS - 1) / ROWS, 256, 0, stream>>>(
        x, u, bt, w1T, w2T, w3T, b1, b2, b3, lng, lnb, out);
    graph2_kernel<<<NGRAPHS / 128, 256, 0, stream>>>(
        u, w4T, w5T, w6T, b4, b5, b6, g2, bb2, out);
}